// Round 4
// baseline (1065.802 us; speedup 1.0000x reference)
//
#include <hip/hip_runtime.h>
#include <hip/hip_bf16.h>

typedef __attribute__((ext_vector_type(8))) short s16x8;
typedef __attribute__((ext_vector_type(4))) float f32x4;

__device__ __forceinline__ unsigned short f2bf(float f){
    __hip_bfloat16 h = __float2bfloat16(f);
    return *reinterpret_cast<unsigned short*>(&h);
}

__device__ __forceinline__ int flab(int g){ return (g < 120) ? 0 : ((g < 124) ? 1 : 2); }

// pack 4 floats -> 4 bf16 in a uint2
__device__ __forceinline__ uint2 pack4(float a, float b, float c, float d){
    uint2 r;
    r.x = (unsigned)f2bf(a) | ((unsigned)f2bf(b) << 16);
    r.y = (unsigned)f2bf(c) | ((unsigned)f2bf(d) << 16);
    return r;
}

// ---------------- weight fp32 -> bf16 ----------------
__global__ __launch_bounds__(256) void wconv_all(
    const float* __restrict__ w0, const float* __restrict__ w1,
    const float* __restrict__ w2, const float* __restrict__ w3,
    unsigned short* __restrict__ o0, unsigned short* __restrict__ o1,
    unsigned short* __restrict__ o2, unsigned short* __restrict__ o3)
{
    int i = blockIdx.x*256 + threadIdx.x;
    if (i < 110592) o0[i] = f2bf(w0[i]);   // qkv_w 576x192
    if (i < 36864)  o1[i] = f2bf(w1[i]);   // proj_w 192x192
    if (i < 147456) o2[i] = f2bf(w2[i]);   // fc1_w 768x192
    if (i < 147456) o3[i] = f2bf(w3[i]);   // fc2_w 192x768
}

// =====================================================================
// LN1 + shift + window + QKV, fused; 1 block/window.
// LN'd tokens -> LDS once; token B-frags hoisted to regs; per o-tile the
// weight A-frags stream from L2; q/k epilogue = direct 8B stores (lane
// holds 4 consecutive d). v goes through a small LDS transpose.
// acc mapping: o = o0+j*16+quad*4+rg, token = wv*16+lrow.
// =====================================================================
__global__ __launch_bounds__(256) void lnqkv_kernel(
    const float* __restrict__ x, const float* __restrict__ g1, const float* __restrict__ b1,
    const unsigned short* __restrict__ wq, const float* __restrict__ qkvb,
    unsigned short* __restrict__ qo, unsigned short* __restrict__ ko,
    unsigned short* __restrict__ vo)
{
    __shared__ __attribute__((aligned(16))) unsigned short win[64*200];  // 25.6KB
    __shared__ __attribute__((aligned(16))) unsigned short T[64*72];     // 9.2KB
    const int b_ = blockIdx.x;
    const int bb = b_>>8, wi = b_&255, wh = wi>>4, ww = wi&15;
    const int tid = threadIdx.x;
    const int wv = tid>>6, lane = tid&63, lrow = lane&15, quad = lane>>4;

    // ---- LN1: thread -> token tid>>2, quarter tid&3 (48 ch) ----
    {
        const int n = tid>>2, q4 = tid&3;
        const int r = n>>3, c = n&7;
        const int hh = (wh*8 + r + 4)&127, wp2 = (ww*8 + c + 4)&127;  // roll(-4)
        const float* px = x + (((size_t)bb*128+hh)*128+wp2)*192 + q4*48;
        float v[48];
        #pragma unroll
        for (int m=0;m<12;++m) *(float4*)(v+m*4) = *(const float4*)(px+m*4);
        float s = 0.f;
        #pragma unroll
        for (int k=0;k<48;++k) s += v[k];
        s += __shfl_xor(s,1); s += __shfl_xor(s,2);
        float mu = s*(1.0f/192.0f);
        float qv = 0.f;
        #pragma unroll
        for (int k=0;k<48;++k){ float d=v[k]-mu; qv += d*d; }
        qv += __shfl_xor(qv,1); qv += __shfl_xor(qv,2);
        float rstd = rsqrtf(qv*(1.0f/192.0f) + 1e-5f);
        const float* pg = g1 + q4*48;
        const float* pb = b1 + q4*48;
        unsigned short* pw = win + n*200 + q4*48;
        #pragma unroll
        for (int k=0;k<48;++k) pw[k] = f2bf((v[k]-mu)*rstd*pg[k] + pb[k]);
    }
    __syncthreads();

    // hoist token B-frags
    s16x8 bfr[6];
    #pragma unroll
    for (int kc=0;kc<6;++kc)
        bfr[kc] = *(const s16x8*)(win + (wv*16+lrow)*200 + kc*32 + quad*8);
    const int token = wv*16 + lrow;

    for (int ot=0; ot<9; ++ot) {
        const int o0 = ot*64;
        f32x4 acc[4];
        #pragma unroll
        for (int j=0;j<4;++j) acc[j] = (f32x4){0.f,0.f,0.f,0.f};
        #pragma unroll
        for (int kc=0;kc<6;++kc)
            #pragma unroll
            for (int j=0;j<4;++j) {
                s16x8 af = *(const s16x8*)(wq + (size_t)(o0 + j*16 + lrow)*192 + kc*32 + quad*8);
                acc[j] = __builtin_amdgcn_mfma_f32_16x16x32_bf16(af, bfr[kc], acc[j], 0, 0, 0);
            }
        const int part = ot/3;                 // 0=q 1=k 2=v
        if (part < 2) {
            unsigned short* dst = (part==0) ? qo : ko;
            const float scale = (part==0) ? 0.17677669529663687f : 1.0f;
            #pragma unroll
            for (int j=0;j<4;++j) {
                int o = o0 + j*16 + quad*4;
                float4 bv = *(const float4*)(qkvb + o);
                int o_in = o - part*192;
                int head = o_in>>5, d = o_in&31;
                uint2 pk = pack4((acc[j][0]+bv.x)*scale, (acc[j][1]+bv.y)*scale,
                                 (acc[j][2]+bv.z)*scale, (acc[j][3]+bv.w)*scale);
                *(uint2*)(dst + (((size_t)b_*6+head)*64 + token)*32 + d) = pk;
            }
        } else {
            #pragma unroll
            for (int j=0;j<4;++j) {
                int o = o0 + j*16 + quad*4;
                float4 bv = *(const float4*)(qkvb + o);
                int ol = j*16 + quad*4;
                T[(ol+0)*72 + token] = f2bf(acc[j][0]+bv.x);
                T[(ol+1)*72 + token] = f2bf(acc[j][1]+bv.y);
                T[(ol+2)*72 + token] = f2bf(acc[j][2]+bv.z);
                T[(ol+3)*72 + token] = f2bf(acc[j][3]+bv.w);
            }
            __syncthreads();
            #pragma unroll
            for (int tt=0;tt<2;++tt) {
                int c = tid + tt*256;          // 0..511
                int ol = c>>3, nb = (c&7)*8;
                int o_in = o0 + ol - 384;
                int head = o_in>>5, d = o_in&31;
                *(int4*)(vo + (((size_t)b_*6+head)*32 + d)*64 + nb) =
                    *(const int4*)(T + ol*72 + nb);
            }
            __syncthreads();
        }
    }
}

// ---------------- windowed attention: 1 block/window, 6 waves = 6 heads ----------------
__global__ __launch_bounds__(384) void attn_kernel(
    const unsigned short* __restrict__ q, const unsigned short* __restrict__ k,
    const unsigned short* __restrict__ vT, const float* __restrict__ rpb,
    unsigned short* __restrict__ ao)
{
    __shared__ float rpb_s[1350];
    __shared__ __attribute__((aligned(16))) unsigned short p_lds[6*4608];
    const int b_ = blockIdx.x;
    const int h = threadIdx.x >> 6;
    const int lane = threadIdx.x & 63, lrow = lane & 15, quad = lane >> 4;
    for (int i = threadIdx.x; i < 1350; i += 384) rpb_s[i] = rpb[i];
    __syncthreads();

    const size_t hb = ((size_t)b_*6 + h)*2048;
    const unsigned short* qb = q  + hb;
    const unsigned short* kb = k  + hb;
    const unsigned short* vb = vT + hb;

    s16x8 qf[4], kf[4];
    #pragma unroll
    for (int i = 0; i < 4; ++i) qf[i] = *(const s16x8*)(qb + (i*16+lrow)*32 + quad*8);
    #pragma unroll
    for (int j = 0; j < 4; ++j) kf[j] = *(const s16x8*)(kb + (j*16+lrow)*32 + quad*8);

    const f32x4 zz = {0.f,0.f,0.f,0.f};
    f32x4 s[4][4];
    #pragma unroll
    for (int i = 0; i < 4; ++i)
        #pragma unroll
        for (int j = 0; j < 4; ++j)
            s[i][j] = __builtin_amdgcn_mfma_f32_16x16x32_bf16(qf[i], kf[j], zz, 0, 0, 0);

    const int wi = b_ & 255, wh = wi >> 4, ww = wi & 15;
    int labm[4];
    #pragma unroll
    for (int j = 0; j < 4; ++j) {
        int m = j*16 + lrow;
        labm[j] = flab(wh*8 + (m >> 3))*3 + flab(ww*8 + (m & 7));
    }
    unsigned short* pl = p_lds + h*4608;
    #pragma unroll
    for (int i = 0; i < 4; ++i) {
        #pragma unroll
        for (int rg = 0; rg < 4; ++rg) {
            int n = i*16 + quad*4 + rg;
            int rn = n >> 3, cn = n & 7;
            int labn = flab(wh*8 + rn)*3 + flab(ww*8 + cn);
            float vals[4];
            float vmax = -1e30f;
            #pragma unroll
            for (int j = 0; j < 4; ++j) {
                int m = j*16 + lrow;
                int idx = ((rn - (m >> 3) + 7)*15 + (cn - (m & 7) + 7))*6 + h;
                float val = s[i][j][rg] + rpb_s[idx];
                if (labn != labm[j]) val -= 100.f;
                vals[j] = val;
                vmax = fmaxf(vmax, val);
            }
            #pragma unroll
            for (int o = 1; o < 16; o <<= 1) vmax = fmaxf(vmax, __shfl_xor(vmax, o));
            float sum = 0.f;
            #pragma unroll
            for (int j = 0; j < 4; ++j) { vals[j] = __expf(vals[j] - vmax); sum += vals[j]; }
            #pragma unroll
            for (int o = 1; o < 16; o <<= 1) sum += __shfl_xor(sum, o);
            float inv = 1.f / sum;
            #pragma unroll
            for (int j = 0; j < 4; ++j) pl[n*72 + j*16 + lrow] = f2bf(vals[j]*inv);
        }
    }
    __syncthreads();

    f32x4 oacc[4][2];
    #pragma unroll
    for (int i = 0; i < 4; ++i) { oacc[i][0] = zz; oacc[i][1] = zz; }
    #pragma unroll
    for (int kc = 0; kc < 2; ++kc) {
        s16x8 vf[2];
        #pragma unroll
        for (int jd = 0; jd < 2; ++jd)
            vf[jd] = *(const s16x8*)(vb + (jd*16+lrow)*64 + kc*32 + quad*8);
        #pragma unroll
        for (int i = 0; i < 4; ++i) {
            s16x8 pf = *(const s16x8*)(pl + (i*16+lrow)*72 + kc*32 + quad*8);
            #pragma unroll
            for (int jd = 0; jd < 2; ++jd)
                oacc[i][jd] = __builtin_amdgcn_mfma_f32_16x16x32_bf16(pf, vf[jd], oacc[i][jd], 0, 0, 0);
        }
    }
    unsigned short* ob = ao + (size_t)b_*12288 + h*32;
    #pragma unroll
    for (int i = 0; i < 4; ++i)
        #pragma unroll
        for (int jd = 0; jd < 2; ++jd)
            #pragma unroll
            for (int rg = 0; rg < 4; ++rg) {
                int n = i*16 + quad*4 + rg;
                ob[(size_t)n*192 + jd*16 + lrow] = f2bf(oacc[i][jd][rg]);
            }
}

// =====================================================================
// proj (full O=192) + window-reverse/roll + residual + LN2. 1 block/window.
// Barrier-free: A=proj_w (L2), B=attnO token frags (hoisted). Each lane
// owns ONE token x 48 o-values; stats via shfl over the 4 quad lanes.
// =====================================================================
__global__ __launch_bounds__(256) void projln_kernel(
    const unsigned short* __restrict__ A, const unsigned short* __restrict__ W,
    const float* __restrict__ pbias, const float* __restrict__ x,
    const float* __restrict__ g2, const float* __restrict__ b2,
    float* __restrict__ x1, unsigned short* __restrict__ xln2)
{
    const int b_ = blockIdx.x;
    const int tid = threadIdx.x, wv = tid>>6, lane = tid&63;
    const int lrow = lane&15, quad = lane>>4;
    const int n2 = wv*16 + lrow;                 // token in window
    const size_t m = (size_t)b_*64 + n2;

    s16x8 bfr[6];
    #pragma unroll
    for (int kc=0;kc<6;++kc)
        bfr[kc] = *(const s16x8*)(A + m*192 + kc*32 + quad*8);

    f32x4 acc[12];
    #pragma unroll
    for (int j=0;j<12;++j) acc[j] = (f32x4){0.f,0.f,0.f,0.f};
    #pragma unroll
    for (int kc=0;kc<6;++kc)
        #pragma unroll
        for (int j=0;j<12;++j) {
            s16x8 af = *(const s16x8*)(W + (size_t)(j*16 + lrow)*192 + kc*32 + quad*8);
            acc[j] = __builtin_amdgcn_mfma_f32_16x16x32_bf16(af, bfr[kc], acc[j], 0, 0, 0);
        }

    const int bb = b_>>8, wi = b_&255, wh = wi>>4, ww = wi&15;
    const int r = n2>>3, c = n2&7;
    const int hh = (wh*8+r+4)&127, wp2 = (ww*8+c+4)&127;   // roll(+4) back
    const size_t tok = ((size_t)bb*128+hh)*128 + wp2;

    float xv[12][4];
    float s = 0.f;
    #pragma unroll
    for (int j=0;j<12;++j) {
        int o = j*16 + quad*4;
        float4 bv = *(const float4*)(pbias + o);
        float4 rx = *(const float4*)(x + tok*192 + o);
        xv[j][0] = acc[j][0]+bv.x+rx.x; xv[j][1] = acc[j][1]+bv.y+rx.y;
        xv[j][2] = acc[j][2]+bv.z+rx.z; xv[j][3] = acc[j][3]+bv.w+rx.w;
        s += xv[j][0]+xv[j][1]+xv[j][2]+xv[j][3];
    }
    s += __shfl_xor(s,16); s += __shfl_xor(s,32);
    float mu = s*(1.0f/192.0f);
    float qv = 0.f;
    #pragma unroll
    for (int j=0;j<12;++j)
        #pragma unroll
        for (int rg=0;rg<4;++rg){ float d = xv[j][rg]-mu; qv += d*d; }
    qv += __shfl_xor(qv,16); qv += __shfl_xor(qv,32);
    float rstd = rsqrtf(qv*(1.0f/192.0f) + 1e-5f);
    #pragma unroll
    for (int j=0;j<12;++j) {
        int o = j*16 + quad*4;
        *(float4*)(x1 + tok*192 + o) = *(const float4*)(xv[j]);
        float4 gv = *(const float4*)(g2 + o);
        float4 b2v = *(const float4*)(b2 + o);
        uint2 pk = pack4((xv[j][0]-mu)*rstd*gv.x + b2v.x, (xv[j][1]-mu)*rstd*gv.y + b2v.y,
                         (xv[j][2]-mu)*rstd*gv.z + b2v.z, (xv[j][3]-mu)*rstd*gv.w + b2v.w);
        *(uint2*)(xln2 + tok*192 + o) = pk;
    }
}

// =====================================================================
// FC1: barrier-free. Block = 128 tokens; B (xln2 frags) hoisted; loop 8
// o-chunks of 96 (j=6). GELU exact (erff). Stores 8B bf16x4.
// =====================================================================
__global__ __launch_bounds__(256) void gemm_fc1_kernel(
    const unsigned short* __restrict__ A, const unsigned short* __restrict__ W,
    const float* __restrict__ bias, unsigned short* __restrict__ h1)
{
    const int tid = threadIdx.x, wv = tid>>6, lane = tid&63;
    const int lrow = lane&15, quad = lane>>4;
    const size_t m0 = (size_t)blockIdx.x*128;

    s16x8 bfr[2][6];
    #pragma unroll
    for (int t=0;t<2;++t)
        #pragma unroll
        for (int kc=0;kc<6;++kc)
            bfr[t][kc] = *(const s16x8*)(A + (m0 + wv*32 + t*16 + lrow)*192 + kc*32 + quad*8);

    for (int oc=0; oc<8; ++oc) {
        f32x4 acc[2][6];
        #pragma unroll
        for (int t=0;t<2;++t)
            #pragma unroll
            for (int j=0;j<6;++j) acc[t][j] = (f32x4){0.f,0.f,0.f,0.f};
        #pragma unroll
        for (int kc=0;kc<6;++kc)
            #pragma unroll
            for (int j=0;j<6;++j) {
                s16x8 af = *(const s16x8*)(W + (size_t)(oc*96 + j*16 + lrow)*192 + kc*32 + quad*8);
                acc[0][j] = __builtin_amdgcn_mfma_f32_16x16x32_bf16(af, bfr[0][kc], acc[0][j], 0, 0, 0);
                acc[1][j] = __builtin_amdgcn_mfma_f32_16x16x32_bf16(af, bfr[1][kc], acc[1][j], 0, 0, 0);
            }
        #pragma unroll
        for (int t=0;t<2;++t) {
            size_t token = m0 + wv*32 + t*16 + lrow;
            #pragma unroll
            for (int j=0;j<6;++j) {
                int o = oc*96 + j*16 + quad*4;
                float4 bv = *(const float4*)(bias + o);
                float v0 = acc[t][j][0]+bv.x, v1 = acc[t][j][1]+bv.y;
                float v2 = acc[t][j][2]+bv.z, v3 = acc[t][j][3]+bv.w;
                v0 = 0.5f*v0*(1.0f+erff(v0*0.7071067811865475f));
                v1 = 0.5f*v1*(1.0f+erff(v1*0.7071067811865475f));
                v2 = 0.5f*v2*(1.0f+erff(v2*0.7071067811865475f));
                v3 = 0.5f*v3*(1.0f+erff(v3*0.7071067811865475f));
                *(uint2*)(h1 + token*768 + o) = pack4(v0,v1,v2,v3);
            }
        }
    }
}

// =====================================================================
// FC2 (K=768): barrier-free. Block = 128 tokens, full O=192 (j=12).
// Residual from x1; float4 stores.
// =====================================================================
__global__ __launch_bounds__(256) void gemm_fc2_kernel(
    const unsigned short* __restrict__ A, const unsigned short* __restrict__ W,
    const float* __restrict__ bias, const float* __restrict__ x1, float* __restrict__ out)
{
    const int tid = threadIdx.x, wv = tid>>6, lane = tid&63;
    const int lrow = lane&15, quad = lane>>4;
    const size_t m0 = (size_t)blockIdx.x*128;

    f32x4 acc[2][12];
    #pragma unroll
    for (int t=0;t<2;++t)
        #pragma unroll
        for (int j=0;j<12;++j) acc[t][j] = (f32x4){0.f,0.f,0.f,0.f};

    #pragma unroll
    for (int kc=0;kc<24;++kc) {
        s16x8 bt[2];
        #pragma unroll
        for (int t=0;t<2;++t)
            bt[t] = *(const s16x8*)(A + (m0 + wv*32 + t*16 + lrow)*768 + kc*32 + quad*8);
        #pragma unroll
        for (int j=0;j<12;++j) {
            s16x8 af = *(const s16x8*)(W + (size_t)(j*16 + lrow)*768 + kc*32 + quad*8);
            acc[0][j] = __builtin_amdgcn_mfma_f32_16x16x32_bf16(af, bt[0], acc[0][j], 0, 0, 0);
            acc[1][j] = __builtin_amdgcn_mfma_f32_16x16x32_bf16(af, bt[1], acc[1][j], 0, 0, 0);
        }
    }
    #pragma unroll
    for (int t=0;t<2;++t) {
        size_t token = m0 + wv*32 + t*16 + lrow;
        #pragma unroll
        for (int j=0;j<12;++j) {
            int o = j*16 + quad*4;
            float4 bv = *(const float4*)(bias + o);
            float4 rx = *(const float4*)(x1 + token*192 + o);
            float4 v;
            v.x = acc[t][j][0]+bv.x+rx.x; v.y = acc[t][j][1]+bv.y+rx.y;
            v.z = acc[t][j][2]+bv.z+rx.z; v.w = acc[t][j][3]+bv.w+rx.w;
            *(float4*)(out + token*192 + o) = v;
        }
    }
}

extern "C" void kernel_launch(void* const* d_in, const int* in_sizes, int n_in,
                              void* d_out, int out_size, void* d_ws, size_t ws_size,
                              hipStream_t stream)
{
    const float* x      = (const float*)d_in[0];
    const float* g1     = (const float*)d_in[1];
    const float* b1     = (const float*)d_in[2];
    const float* qkv_w  = (const float*)d_in[3];
    const float* qkv_b  = (const float*)d_in[4];
    const float* rpb    = (const float*)d_in[5];
    const float* proj_w = (const float*)d_in[6];
    const float* proj_b = (const float*)d_in[7];
    const float* g2     = (const float*)d_in[8];
    const float* b2     = (const float*)d_in[9];
    const float* fc1_w  = (const float*)d_in[10];
    const float* fc1_b  = (const float*)d_in[11];
    const float* fc2_w  = (const float*)d_in[12];
    const float* fc2_b  = (const float*)d_in[13];
    float* out = (float*)d_out;
    char* ws = (char*)d_ws;

    if (ws_size < 353206272ULL) return;

    unsigned short* qbuf  = (unsigned short*)(ws + 0);          // 50.3MB
    unsigned short* kbuf  = (unsigned short*)(ws + 50331648);   // 50.3MB
    unsigned short* vbuf  = (unsigned short*)(ws + 100663296);  // 50.3MB (vT)
    unsigned short* attnO = (unsigned short*)(ws + 150994944);  // 50.3MB
    float*          x1    = (float*)        (ws + 201326592);   // 100.7MB
    unsigned short* xln2  = (unsigned short*)(ws + 301989888);  // 50.3MB
    unsigned short* wq    = (unsigned short*)(ws + 352321536);
    unsigned short* wp    = (unsigned short*)(ws + 352321536 + 221184);
    unsigned short* w1    = (unsigned short*)(ws + 352321536 + 221184 + 73728);
    unsigned short* w2    = (unsigned short*)(ws + 352321536 + 221184 + 73728 + 294912);
    unsigned short* h1    = (unsigned short*)(ws + 0);          // overlays q,k,v,attnO

    wconv_all<<<576, 256, 0, stream>>>(qkv_w, proj_w, fc1_w, fc2_w, wq, wp, w1, w2);
    lnqkv_kernel<<<2048, 256, 0, stream>>>(x, g1, b1, wq, qkv_b, qbuf, kbuf, vbuf);
    attn_kernel<<<2048, 384, 0, stream>>>(qbuf, kbuf, vbuf, rpb, attnO);
    projln_kernel<<<2048, 256, 0, stream>>>(attnO, wp, proj_b, x, g2, b2, x1, xln2);
    gemm_fc1_kernel<<<1024, 256, 0, stream>>>(xln2, w1, fc1_b, h1);
    gemm_fc2_kernel<<<1024, 256, 0, stream>>>(h1, w2, fc2_b, x1, out);
}